// Round 5
// baseline (358.707 us; speedup 1.0000x reference)
//
#include <hip/hip_runtime.h>
#include <math.h>

// Problem constants
#define S 192
#define H 64
#define NH 8           // b*n = 1*8
#define SC 0.125f
#define FILLV (-1000000.0f)

// ---------------- wave (64-lane) reductions ----------------
__device__ __forceinline__ float wave_max(float v) {
#pragma unroll
  for (int m = 32; m; m >>= 1) v = fmaxf(v, __shfl_xor(v, m));
  return v;
}
__device__ __forceinline__ float wave_sum(float v) {
#pragma unroll
  for (int m = 32; m; m >>= 1) v += __shfl_xor(v, m);
  return v;
}

// ---------------- Kernel A: 4 small GEMMs + silu ----------------
// 32x32 tiles, K=64. 288 tiles per product (8 heads x 6x6).
//   p=0: kk  = k1*k2^T   p=1: qk  = k2*q^T
//   p=2: kkT = k2*k1^T   p=3: qkT = q*k2^T
// blocks 1152..1247: silu(v1) float4 elementwise
__global__ __launch_bounds__(256) void prep_kernel(
    const float* __restrict__ q, const float* __restrict__ k1,
    const float* __restrict__ k2, const float* __restrict__ v1,
    float* __restrict__ kk, float* __restrict__ qk,
    float* __restrict__ kkT, float* __restrict__ qkT,
    float* __restrict__ sv1) {
  int b = blockIdx.x;
  if (b < 1152) {
    int p = b / 288, bb = b % 288;
    int n = bb / 36, rem = bb % 36;
    int rt = (rem / 6) * 32;   // row tile base
    int ct = (rem % 6) * 32;   // col tile base
    const float* Abase;
    const float* Bbase;
    float* out;
    if (p == 0)      { Abase = k1; Bbase = k2; out = kk; }
    else if (p == 1) { Abase = k2; Bbase = q;  out = qk; }
    else if (p == 2) { Abase = k2; Bbase = k1; out = kkT; }
    else             { Abase = q;  Bbase = k2; out = qkT; }
    Abase += n * S * H; Bbase += n * S * H; out += n * S * S;

    __shared__ float As[32][65];
    __shared__ float Bs[32][65];
    int tid = threadIdx.x;
    for (int i = tid; i < 32 * 64; i += 256) {
      int r = i >> 6, h = i & 63;
      As[r][h] = Abase[(rt + r) * H + h];
      Bs[r][h] = Bbase[(ct + r) * H + h];
    }
    __syncthreads();
    int r0 = (tid / 16) * 2, c0 = (tid % 16) * 2;
    float a00 = 0.f, a01 = 0.f, a10 = 0.f, a11 = 0.f;
#pragma unroll
    for (int h = 0; h < 64; ++h) {
      float x0 = As[r0][h], x1 = As[r0 + 1][h];
      float y0 = Bs[c0][h], y1 = Bs[c0 + 1][h];
      a00 += x0 * y0; a01 += x0 * y1; a10 += x1 * y0; a11 += x1 * y1;
    }
    out[(rt + r0) * S + ct + c0]         = a00;
    out[(rt + r0) * S + ct + c0 + 1]     = a01;
    out[(rt + r0 + 1) * S + ct + c0]     = a10;
    out[(rt + r0 + 1) * S + ct + c0 + 1] = a11;
  } else {
    int i = (b - 1152) * 256 + threadIdx.x;   // 96 blocks * 256 = 24576 float4
    const float4* v4 = (const float4*)v1;
    float4 x = v4[i];
    float4 y;
    y.x = x.x / (1.f + expf(-x.x));
    y.y = x.y / (1.f + expf(-x.y));
    y.z = x.z / (1.f + expf(-x.z));
    y.w = x.w / (1.f + expf(-x.w));
    ((float4*)sv1)[i] = y;
  }
}

// ---------------- Kernel D: per-t stats m_t, S_t and A[t,h] ----------------
// grid = NH*S blocks, 256 threads (4 waves). Reads kkT rows (coalesced).
__global__ __launch_bounds__(256) void stats_kernel(
    const float* __restrict__ kkT, const float* __restrict__ sv1,
    float* __restrict__ mt, float* __restrict__ St, float* __restrict__ Aw) {
  int n = blockIdx.x / S, t = blockIdx.x % S;
  int tid = threadIdx.x, wv = tid >> 6, lane = tid & 63;
  __shared__ float w[S];
  __shared__ float red[4];
  __shared__ float part[4][H];
  const float* kkr = kkT + n * S * S + t * S;  // kkr[s] = kk[s][t]

  float lm = -3.4e38f;
  for (int s = tid; s <= t; s += 256) lm = fmaxf(lm, SC * kkr[s]);
  lm = wave_max(lm);
  if (lane == 0) red[wv] = lm;
  __syncthreads();
  float m = fmaxf(fmaxf(red[0], red[1]), fmaxf(red[2], red[3]));

  float ls = 0.f;
  for (int s = tid; s <= t; s += 256) {
    float e = expf(SC * kkr[s] - m);
    w[s] = e;
    ls += e;
  }
  ls = wave_sum(ls);
  __syncthreads();
  if (lane == 0) red[wv] = ls;
  __syncthreads();
  float Ssum = red[0] + red[1] + red[2] + red[3];
  if (tid == 0) { mt[n * S + t] = m; St[n * S + t] = Ssum; }

  // A[t,h] = sum_{s<=t} w[s]*sv1[s,h]; 4 waves split s, lane = h
  const float* sh = sv1 + n * S * H + lane;
  float acc = 0.f;
  for (int s = wv; s <= t; s += 4) acc += w[s] * sh[s * H];
  part[wv][lane] = acc;
  __syncthreads();
  if (wv == 0)
    Aw[(n * S + t) * H + lane] = part[0][lane] + part[1][lane] + part[2][lane] + part[3][lane];
}

// ---------------- Kernel E: per-q M0, D, z, M ----------------
// grid = NH*S blocks, 256 threads (4 waves). Reads qkT rows (coalesced).
__global__ __launch_bounds__(256) void out_kernel(
    const float* __restrict__ qkT, const float* __restrict__ v2,
    const float* __restrict__ mt, const float* __restrict__ St,
    const float* __restrict__ Aw,
    float* __restrict__ z, float* __restrict__ Mout) {
  int n = blockIdx.x / S, qq = blockIdx.x % S;
  int tid = threadIdx.x, wv = tid >> 6, lane = tid & 63;
  __shared__ float e[S];
  __shared__ float red[4];
  __shared__ float part[4][H];
  const float* qkr = qkT + n * S * S + qq * S;  // qkr[t] = qk[t][q]
  const float* mtp = mt + n * S;
  const float* Stp = St + n * S;

  float lm = -3.4e38f;
  for (int t = tid; t <= qq; t += 256) lm = fmaxf(lm, SC * qkr[t] + mtp[t]);
  lm = wave_max(lm);
  if (lane == 0) red[wv] = lm;
  __syncthreads();
  float M0 = fmaxf(fmaxf(red[0], red[1]), fmaxf(red[2], red[3]));

  float ls = 0.f;
  for (int t = tid; t <= qq; t += 256) {
    float ev = expf(SC * qkr[t] + mtp[t] - M0);
    e[t] = ev;
    ls += ev * Stp[t];
  }
  ls = wave_sum(ls);
  __syncthreads();
  if (lane == 0) red[wv] = ls;
  __syncthreads();
  float D = red[0] + red[1] + red[2] + red[3];
  if (tid == 0) Mout[n * S + qq] = M0 + logf(D + 0.01f);

  const float* vh = v2 + n * S * H + lane;
  const float* Ah = Aw + n * S * H + lane;
  float acc = 0.f;
  for (int t = wv; t <= qq; t += 4) acc += e[t] * vh[t * H] * Ah[t * H];
  part[wv][lane] = acc;
  __syncthreads();
  if (wv == 0)
    z[(n * S + qq) * H + lane] =
        (part[0][lane] + part[1][lane] + part[2][lane] + part[3][lane]) / D;
}

// ---------------- Kernel F: fused output streams ----------------
// blocks 0..1535   : score slice (n,s): [192 t][192 q] floats (147 KB)
// blocks 1536..3071: v_gated slice (n,s): [192 t][64 h] floats (48 KB)
// 384 threads; division-free inner loops; plain float4 stores.
__global__ __launch_bounds__(384) void stream_kernel(
    const float* __restrict__ kk, const float* __restrict__ qk,
    const float* __restrict__ sv1, const float* __restrict__ v2,
    float* __restrict__ score, float* __restrict__ vg) {
  int b = blockIdx.x;
  int tid = threadIdx.x;
  if (b < 1536) {
    int n = b / S, s = b % S;
    const float* kkr = kk + (n * S + s) * S;          // kk[s][t]
    const float4* qk4 = (const float4*)(qk + n * S * S);
    float4* out4 = (float4*)(score + (size_t)(n * S + s) * S * S);
    int r = tid / 48;        // 8 rows per iteration (384 = 8*48)
    int j = tid % 48;        // float4 column within row
    int q0 = 4 * j;
#pragma unroll 4
    for (int tbase = 0; tbase < S; tbase += 8) {
      int t = tbase + r;
      float kv = kkr[t];
      float4 qv = qk4[t * 48 + j];
      bool rowmask = (t < s);
      float4 v;
      v.x = (rowmask || t > q0)     ? FILLV : kv + qv.x;
      v.y = (rowmask || t > q0 + 1) ? FILLV : kv + qv.y;
      v.z = (rowmask || t > q0 + 2) ? FILLV : kv + qv.z;
      v.w = (rowmask || t > q0 + 3) ? FILLV : kv + qv.w;
      out4[t * 48 + j] = v;
    }
  } else {
    int bb = b - 1536;
    int n = bb / S, s = bb % S;
    const float4* a4 = (const float4*)(sv1 + (n * S + s) * H);
    const float4* b4 = (const float4*)(v2 + n * S * H);
    float4* out4 = (float4*)(vg + (size_t)(n * S + s) * S * H);
#pragma unroll
    for (int it = 0; it < 8; ++it) {                  // 3072 float4 / 384
      int i = it * 384 + tid;
      int t = i >> 4, j = i & 15;
      float4 a = a4[j];
      float4 bv = b4[t * 16 + j];
      out4[i] = make_float4(a.x * bv.x, a.y * bv.y, a.z * bv.z, a.w * bv.w);
    }
  }
}

extern "C" void kernel_launch(void* const* d_in, const int* in_sizes, int n_in,
                              void* d_out, int out_size, void* d_ws, size_t ws_size,
                              hipStream_t stream) {
  const float* q  = (const float*)d_in[0];
  const float* k1 = (const float*)d_in[1];
  const float* k2 = (const float*)d_in[2];
  const float* v1 = (const float*)d_in[3];
  const float* v2 = (const float*)d_in[4];
  float* out = (float*)d_out;

  // Output layout (concatenated flat, return order): z, pre_score, v_gated, M
  float* z     = out;                                  // 8*192*64       = 98304
  float* score = out + 98304;                          // 8*192*192*192  = 56623104
  float* vg    = out + 98304 + 56623104;               // 8*192*192*64   = 18874368
  float* Mout  = out + 98304 + 56623104 + 18874368;    // 8*192          = 1536

  // Workspace layout (floats)
  float* ws   = (float*)d_ws;
  float* kk   = ws;                  // 294912
  float* qk   = ws + 294912;         // 294912
  float* kkT  = ws + 589824;         // 294912
  float* qkT  = ws + 884736;         // 294912
  float* sv1  = ws + 1179648;        // 98304
  float* mt   = ws + 1277952;        // 1536
  float* St   = ws + 1279488;        // 1536
  float* Aw   = ws + 1281024;        // 98304  -> total ~5.5 MB

  prep_kernel<<<dim3(1248), dim3(256), 0, stream>>>(q, k1, k2, v1, kk, qk, kkT, qkT, sv1);
  stats_kernel<<<dim3(NH * S), dim3(256), 0, stream>>>(kkT, sv1, mt, St, Aw);
  out_kernel<<<dim3(NH * S), dim3(256), 0, stream>>>(qkT, v2, mt, St, Aw, z, Mout);
  stream_kernel<<<dim3(3072), dim3(384), 0, stream>>>(kk, qk, sv1, v2, score, vg);
}